// Round 1
// baseline (244.567 us; speedup 1.0000x reference)
//
#include <hip/hip_runtime.h>
#include <math.h>

#define KK 5
#define KN 32
#define CIN 16
#define H 64
#define W 64
#define NB 32
#define HO 60
#define WO 60
#define D_TOT 400   // KK*KK*CIN
#define TILE 16
#define TIN 20      // TILE + KK - 1
#define NPIX (TIN*TIN)   // 400
#define OUT_PLANE (NB*HO*WO*KN)  // 3686400

__device__ __forceinline__ float softplusf(float x) {
    return (x > 20.0f) ? x : log1pf(__expf(x));
}

// wbuf[d*64 + kn]      = w_mu[d][kn]
// wbuf[d*64 + 32 + kn] = w_mu[d][kn]^2 / 400
__global__ void prep_weights(const float* __restrict__ w_mu, float* __restrict__ wbuf) {
    int idx = blockIdx.x * 256 + threadIdx.x;
    if (idx < D_TOT * KN) {
        float w = w_mu[idx];
        int d = idx >> 5, kn = idx & 31;
        wbuf[d * 64 + kn] = w;
        wbuf[d * 64 + 32 + kn] = w * w * (1.0f / 400.0f);
    }
}

// KL scalar + spw[kn] = softplus(w_sigma[kn]) / 400
__global__ void kl_and_spw(const float* __restrict__ w_mu, const float* __restrict__ w_sigma,
                           float* __restrict__ spw, float* __restrict__ kl_out) {
    __shared__ float red[256];
    int t = threadIdx.x;
    float s = 0.f;
    for (int i = t; i < D_TOT * KN; i += 256) { float w = w_mu[i]; s += w * w; }
    red[t] = s;
    __syncthreads();
    for (int off = 128; off > 0; off >>= 1) {
        if (t < off) red[t] += red[t + off];
        __syncthreads();
    }
    float sum_w2 = red[0];
    if (t < KN) {
        float ws = w_sigma[t];
        spw[t] = log1pf(expf(ws)) * (1.0f / 400.0f);
    }
    if (t == 0) {
        float sws = 0.f;
        for (int kn = 0; kn < KN; ++kn) {
            float ws = w_sigma[kn];
            float sp = log1pf(expf(ws));
            sws += -ws + sp * 100.0f;   // 1/PRIOR_VAR = 100
        }
        // kl = 0.5*( log(0.01) - 1 + mean_kn(-ws + sp/0.01) + mean(w_mu^2)/0.01 )
        float kl = 0.5f * (-4.605170186f - 1.0f + sws * (1.0f / 32.0f)
                           + sum_w2 * (100.0f / 12800.0f));
        *kl_out = kl;
    }
}

__global__ __launch_bounds__(256)
void vdp_main(const float* __restrict__ mu_in, const float* __restrict__ sig_in,
              const float* __restrict__ wbuf, const float* __restrict__ spw,
              float* __restrict__ mu_out, float* __restrict__ sig_out) {
    __shared__ float smu[CIN * NPIX];
    __shared__ float ssg[CIN * NPIX];

    const int b   = blockIdx.z;
    const int ho0 = blockIdx.y * TILE;
    const int wo0 = blockIdx.x * TILE;
    const int t   = threadIdx.x;

    // ---- stage 20x20x16 tiles of mu and Sigma into LDS (channel-major) ----
    for (int i = t; i < NPIX * 4; i += 256) {
        int pos = i >> 2, c4 = i & 3;
        int py = pos / TIN, px = pos - py * TIN;
        int gh = ho0 + py, gw = wo0 + px;
        float4 vm = make_float4(0.f, 0.f, 0.f, 0.f);
        float4 vs = vm;
        if (gh < H && gw < W) {
            size_t gbase = (((size_t)b * H + gh) * W + gw) * CIN + c4 * 4;
            vm = *(const float4*)(mu_in + gbase);
            vs = *(const float4*)(sig_in + gbase);
        }
        int c0 = c4 * 4;
        smu[(c0 + 0) * NPIX + pos] = vm.x;
        smu[(c0 + 1) * NPIX + pos] = vm.y;
        smu[(c0 + 2) * NPIX + pos] = vm.z;
        smu[(c0 + 3) * NPIX + pos] = vm.w;
        ssg[(c0 + 0) * NPIX + pos] = vs.x;
        ssg[(c0 + 1) * NPIX + pos] = vs.y;
        ssg[(c0 + 2) * NPIX + pos] = vs.z;
        ssg[(c0 + 3) * NPIX + pos] = vs.w;
    }
    __syncthreads();

    const int ty = t >> 4, tx = t & 15;

    float accm[KN], accs[KN];
#pragma unroll
    for (int kn = 0; kn < KN; ++kn) { accm[kn] = 0.f; accs[kn] = 0.f; }
    float t1 = 0.f, t2 = 0.f;

    for (int kh = 0; kh < KK; ++kh) {
        for (int kw = 0; kw < KK; ++kw) {
            const int pos = (ty + kh) * TIN + tx + kw;
            const float* wr = wbuf + ((kh * KK + kw) * CIN) * 64;
            for (int c = 0; c < CIN; ++c) {
                float pmu = smu[c * NPIX + pos];
                float psg = ssg[c * NPIX + pos];
                t1 += psg;
                t2 = fmaf(pmu, pmu, t2);
                const float* wrow = wr + c * 64;   // wave-uniform -> s_load
#pragma unroll
                for (int kn = 0; kn < KN; ++kn)
                    accm[kn] = fmaf(pmu, wrow[kn], accm[kn]);
#pragma unroll
                for (int kn = 0; kn < KN; ++kn)
                    accs[kn] = fmaf(psg, wrow[32 + kn], accs[kn]);
            }
        }
    }

    const int ho = ho0 + ty, wo = wo0 + tx;
    if (ho < HO && wo < WO) {
        const float t12 = t1 + t2;
        size_t obase = (((size_t)b * HO + ho) * WO + wo) * KN;
        float om[KN], os[KN];
#pragma unroll
        for (int kn = 0; kn < KN; ++kn) {
            om[kn] = accm[kn];
            float pre = accs[kn] + t12 * spw[kn];
            os[kn] = softplusf(pre);
        }
        float4* pm = (float4*)(mu_out + obase);
        float4* ps = (float4*)(sig_out + obase);
#pragma unroll
        for (int q = 0; q < 8; ++q) {
            pm[q] = ((float4*)om)[q];
            ps[q] = ((float4*)os)[q];
        }
    }
}

extern "C" void kernel_launch(void* const* d_in, const int* in_sizes, int n_in,
                              void* d_out, int out_size, void* d_ws, size_t ws_size,
                              hipStream_t stream) {
    const float* mu_in   = (const float*)d_in[0];
    const float* sig_in  = (const float*)d_in[1];
    const float* w_mu    = (const float*)d_in[2];
    const float* w_sigma = (const float*)d_in[3];

    float* out     = (float*)d_out;
    float* mu_out  = out;
    float* sig_out = out + (size_t)OUT_PLANE;
    float* kl_out  = out + 2 * (size_t)OUT_PLANE;

    float* wbuf = (float*)d_ws;            // 400*64 = 25600 floats
    float* spw  = wbuf + D_TOT * 64;       // 32 floats

    prep_weights<<<50, 256, 0, stream>>>(w_mu, wbuf);
    kl_and_spw<<<1, 256, 0, stream>>>(w_mu, w_sigma, spw, kl_out);
    vdp_main<<<dim3((WO + TILE - 1) / TILE, (HO + TILE - 1) / TILE, NB), 256, 0, stream>>>(
        mu_in, sig_in, wbuf, spw, mu_out, sig_out);
}

// Round 2
// 112.514 us; speedup vs baseline: 2.1737x; 2.1737x over previous
//
#include <hip/hip_runtime.h>
#include <hip/hip_bf16.h>
#include <math.h>

#define KK 5
#define KN 32
#define CIN 16
#define H 64
#define W 64
#define NB 32
#define HO 60
#define WO 60
#define D_TOT 400
#define OUT_PLANE (NB*HO*WO*KN)

// block tile: 8 out-rows x 16 out-cols, 4 waves, each wave 2 rows
#define TH 8
#define TW 16
#define IN_R 12      // TH + KK - 1
#define IN_C 20      // TW + KK - 1
#define CPAD 24      // c padded 16 -> 24 shorts (48B col stride: 2-way banks, free)
#define TILE_SH (IN_R*IN_C*CPAD)   // 5760 shorts per map
#define NKSTEP 13                  // ceil(400/32)

typedef short short8 __attribute__((ext_vector_type(8)));
typedef float f32x4 __attribute__((ext_vector_type(4)));

__device__ __forceinline__ ushort f2bf(float x) {
    __hip_bfloat16 h = __float2bfloat16(x);
    return *reinterpret_cast<ushort*>(&h);
}
__device__ __forceinline__ float bf2f(ushort u) {
    __hip_bfloat16 h = *reinterpret_cast<__hip_bfloat16*>(&u);
    return __bfloat162float(h);
}
__device__ __forceinline__ float softplusf(float x) {
    return (x > 20.0f) ? x : __logf(1.0f + __expf(x));
}

// ---------------- prep: pack B fragments + spw + KL ----------------
// Bpack layout (short8 frags): idx8 = (t*2 + nt)*64 + lane ; element j:
//   k = t*32 + ((lane>>4)&3)*8 + j ; n = nt*16 + (lane&15); zero for k>=400
// ws: Bmu[13312 shorts] | Bsq[13312 shorts] | spw[32 floats]
__global__ void prep_all(const float* __restrict__ w_mu, const float* __restrict__ w_sigma,
                         ushort* __restrict__ bmu, ushort* __restrict__ bsq,
                         float* __restrict__ spw, float* __restrict__ kl_out) {
    __shared__ float red[256];
    int t = threadIdx.x;
    if (blockIdx.x < 52) {
        int idx = blockIdx.x * 256 + t;     // < 13312
        int j  = idx & 7;
        int l  = (idx >> 3) & 63;
        int nt = (idx >> 9) & 1;
        int ts = idx >> 10;
        int k  = ts * 32 + ((l >> 4) & 3) * 8 + j;
        int n  = nt * 16 + (l & 15);
        float w = (k < D_TOT) ? w_mu[k * KN + n] : 0.0f;
        bmu[idx] = f2bf(w);
        bsq[idx] = f2bf(w * w * (1.0f / 400.0f));
    } else {
        // KL + spw block
        float s = 0.f;
        for (int i = t; i < D_TOT * KN; i += 256) { float w = w_mu[i]; s += w * w; }
        red[t] = s;
        __syncthreads();
        for (int off = 128; off > 0; off >>= 1) {
            if (t < off) red[t] += red[t + off];
            __syncthreads();
        }
        float sum_w2 = red[0];
        if (t < KN) {
            float ws = w_sigma[t];
            spw[t] = log1pf(expf(ws)) * (1.0f / 400.0f);
        }
        if (t == 0) {
            float sws = 0.f;
            for (int kn = 0; kn < KN; ++kn) {
                float ws = w_sigma[kn];
                float sp = log1pf(expf(ws));
                sws += -ws + sp * 100.0f;
            }
            float kl = 0.5f * (-4.605170186f - 1.0f + sws * (1.0f / 32.0f)
                               + sum_w2 * (100.0f / 12800.0f));
            *kl_out = kl;
        }
    }
}

// ---------------- main ----------------
__global__ __launch_bounds__(256, 4)
void vdp_main(const float* __restrict__ mu_in, const float* __restrict__ sig_in,
              const ushort* __restrict__ bmu_g, const ushort* __restrict__ bsq_g,
              const float* __restrict__ spw,
              float* __restrict__ mu_out, float* __restrict__ sig_out) {
    // LDS: [mu tile 5760][sg tile 5760][zero pad 8] shorts + csum + t12
    __shared__ ushort tiles[2 * TILE_SH + 8];
    __shared__ float csum[IN_R * IN_C];   // per input pixel: sum_c (sigma + mu^2)
    __shared__ float t12s[TH * TW];

    const int b   = blockIdx.z;
    const int ho0 = blockIdx.y * TH;
    const int wo0 = blockIdx.x * TW;
    const int t   = threadIdx.x;

    if (t < 8) tiles[2 * TILE_SH + t] = 0;   // zero pad for k>=400 A reads

    // ---- stage 12x20x16 fp32 -> bf16 LDS (c-padded to 24) ----
    for (int i = t; i < IN_R * IN_C * 4; i += 256) {   // 960 float4 per map
        int row = i / 80;
        int rem = i - row * 80;
        int col = rem >> 2, c4 = rem & 3;
        int gh = ho0 + row, gw = wo0 + col;
        float4 vm = make_float4(0.f, 0.f, 0.f, 0.f), vs = vm;
        if (gh < H && gw < W) {
            size_t g = (((size_t)b * H + gh) * W + gw) * CIN + c4 * 4;
            vm = *(const float4*)(mu_in + g);
            vs = *(const float4*)(sig_in + g);
        }
        int sb = (row * IN_C + col) * CPAD + c4 * 4;
        ushort4 um, us;
        um.x = f2bf(vm.x); um.y = f2bf(vm.y); um.z = f2bf(vm.z); um.w = f2bf(vm.w);
        us.x = f2bf(vs.x); us.y = f2bf(vs.y); us.z = f2bf(vs.z); us.w = f2bf(vs.w);
        *(ushort4*)&tiles[sb] = um;
        *(ushort4*)&tiles[TILE_SH + sb] = us;
    }
    __syncthreads();

    // ---- per-input-pixel channel sums: csum = sum_c(sigma + mu^2) ----
    if (t < IN_R * IN_C) {
        int sb = t * CPAD;
        float acc = 0.f;
#pragma unroll
        for (int g = 0; g < 4; ++g) {
            ushort4 m4 = *(ushort4*)&tiles[sb + g * 4];
            ushort4 s4 = *(ushort4*)&tiles[TILE_SH + sb + g * 4];
            float m0 = bf2f(m4.x), m1 = bf2f(m4.y), m2 = bf2f(m4.z), m3 = bf2f(m4.w);
            acc += bf2f(s4.x) + bf2f(s4.y) + bf2f(s4.z) + bf2f(s4.w);
            acc += m0 * m0 + m1 * m1 + m2 * m2 + m3 * m3;
        }
        csum[t] = acc;
    }
    __syncthreads();

    // ---- 5x5 window sums: t12 per output pixel ----
    if (t < TH * TW) {
        int r = t >> 4, c = t & 15;
        float s = 0.f;
#pragma unroll
        for (int kh = 0; kh < KK; ++kh)
#pragma unroll
            for (int kw = 0; kw < KK; ++kw)
                s += csum[(r + kh) * IN_C + c + kw];
        t12s[t] = s;
    }
    __syncthreads();

    // ---- MFMA k-loop ----
    const int w    = t >> 6;
    const int l    = t & 63;
    const int col  = l & 15;
    const int q    = l >> 4;
    const int qh   = q >> 1;         // which (kh,kw) position within kstep pair
    const int qc   = q & 1;          // which c-half (0..7 / 8..15)

    const char* lds = (const char*)tiles;
    // per-mt per-mat fragment bases (bytes), without kh/kw offset
    int base0 = ((2 * w + 0) * IN_C + col) * (CPAD * 2) + qc * 16;
    int base1 = ((2 * w + 1) * IN_C + col) * (CPAD * 2) + qc * 16;
    const int qh48  = qh * 48;
    const int qh768 = qh * 768;
    const int zpad  = 2 * TILE_SH * 2;   // byte offset of zero pad

    const short8* Bmu8 = (const short8*)bmu_g;
    const short8* Bsq8 = (const short8*)bsq_g;

    f32x4 accm[2][2], accs[2][2];
    f32x4 z = {0.f, 0.f, 0.f, 0.f};
#pragma unroll
    for (int a = 0; a < 2; ++a)
#pragma unroll
        for (int bn = 0; bn < 2; ++bn) { accm[a][bn] = z; accs[a][bn] = z; }

    // F(2t) = (kh*20+kw) spatial offset for even position; D16: row-crossing pairs
    constexpr int F0v[NKSTEP]  = {0, 2, 4, 21, 23, 40, 42, 44, 61, 63, 80, 82, 84};
    constexpr int D16[NKSTEP] = {0, 0, 1, 0, 0, 0, 0, 1, 0, 0, 0, 0, 2};

#pragma unroll
    for (int ts = 0; ts < NKSTEP; ++ts) {
        short8 am0, am1, as0, as1;
        if (D16[ts] == 2) {  // last step: odd position (p=25) is padding -> zeros
            int a0 = qh ? zpad : (base0 + F0v[ts] * 48);
            int a1 = qh ? zpad : (base1 + F0v[ts] * 48);
            am0 = *(const short8*)(lds + a0);
            am1 = *(const short8*)(lds + a1);
            as0 = *(const short8*)(lds + a0 + (qh ? 0 : TILE_SH * 2));
            as1 = *(const short8*)(lds + a1 + (qh ? 0 : TILE_SH * 2));
        } else {
            int ex = (D16[ts] ? qh768 : qh48) + F0v[ts] * 48;
            am0 = *(const short8*)(lds + base0 + ex);
            am1 = *(const short8*)(lds + base1 + ex);
            as0 = *(const short8*)(lds + TILE_SH * 2 + base0 + ex);
            as1 = *(const short8*)(lds + TILE_SH * 2 + base1 + ex);
        }
        short8 bm0 = Bmu8[(ts * 2 + 0) * 64 + l];
        short8 bm1 = Bmu8[(ts * 2 + 1) * 64 + l];
        short8 bs0 = Bsq8[(ts * 2 + 0) * 64 + l];
        short8 bs1 = Bsq8[(ts * 2 + 1) * 64 + l];

        accm[0][0] = __builtin_amdgcn_mfma_f32_16x16x32_bf16(am0, bm0, accm[0][0], 0, 0, 0);
        accm[0][1] = __builtin_amdgcn_mfma_f32_16x16x32_bf16(am0, bm1, accm[0][1], 0, 0, 0);
        accm[1][0] = __builtin_amdgcn_mfma_f32_16x16x32_bf16(am1, bm0, accm[1][0], 0, 0, 0);
        accm[1][1] = __builtin_amdgcn_mfma_f32_16x16x32_bf16(am1, bm1, accm[1][1], 0, 0, 0);
        accs[0][0] = __builtin_amdgcn_mfma_f32_16x16x32_bf16(as0, bs0, accs[0][0], 0, 0, 0);
        accs[0][1] = __builtin_amdgcn_mfma_f32_16x16x32_bf16(as0, bs1, accs[0][1], 0, 0, 0);
        accs[1][0] = __builtin_amdgcn_mfma_f32_16x16x32_bf16(as1, bs0, accs[1][0], 0, 0, 0);
        accs[1][1] = __builtin_amdgcn_mfma_f32_16x16x32_bf16(as1, bs1, accs[1][1], 0, 0, 0);
    }

    // ---- epilogue ----
    // C/D: row(pixel-col within tile) = q*4 + reg, col(channel) = l&15 (+16*nt)
    float spw0 = spw[col], spw1 = spw[16 + col];
#pragma unroll
    for (int mt = 0; mt < 2; ++mt) {
        int ho = ho0 + 2 * w + mt;
        if (ho >= HO) continue;
#pragma unroll
        for (int reg = 0; reg < 4; ++reg) {
            int wo = wo0 + q * 4 + reg;
            if (wo >= WO) continue;
            float t12v = t12s[(2 * w + mt) * TW + q * 4 + reg];
            size_t base = (((size_t)b * HO + ho) * WO + wo) * KN;
            mu_out[base + col]      = accm[mt][0][reg];
            mu_out[base + 16 + col] = accm[mt][1][reg];
            float s0 = accs[mt][0][reg] + t12v * spw0;
            float s1 = accs[mt][1][reg] + t12v * spw1;
            sig_out[base + col]      = softplusf(s0);
            sig_out[base + 16 + col] = softplusf(s1);
        }
    }
}

extern "C" void kernel_launch(void* const* d_in, const int* in_sizes, int n_in,
                              void* d_out, int out_size, void* d_ws, size_t ws_size,
                              hipStream_t stream) {
    const float* mu_in   = (const float*)d_in[0];
    const float* sig_in  = (const float*)d_in[1];
    const float* w_mu    = (const float*)d_in[2];
    const float* w_sigma = (const float*)d_in[3];

    float* out     = (float*)d_out;
    float* mu_out  = out;
    float* sig_out = out + (size_t)OUT_PLANE;
    float* kl_out  = out + 2 * (size_t)OUT_PLANE;

    ushort* bmu = (ushort*)d_ws;                    // 13312 shorts
    ushort* bsq = bmu + 13312;                      // 13312 shorts
    float*  spw = (float*)(bsq + 13312);            // 32 floats

    prep_all<<<53, 256, 0, stream>>>(w_mu, w_sigma, bmu, bsq, spw, kl_out);
    vdp_main<<<dim3(4, 8, NB), 256, 0, stream>>>(mu_in, sig_in, bmu, bsq, spw,
                                                 mu_out, sig_out);
}